// Round 2
// baseline (2037.462 us; speedup 1.0000x reference)
//
#include <hip/hip_runtime.h>

#define DD 8
#define SS 64
#define HH 128
#define OUTD 8
#define TT 2049
#define BB 32
#define WINW 16
#define NWIN 128
#define PP 28

typedef __attribute__((ext_vector_type(8))) short short8v;
typedef __attribute__((ext_vector_type(4))) float f32x4;

__device__ __forceinline__ float softplus_f(float x){
    return fmaxf(x, 0.f) + log1pf(__expf(-fabsf(x)));
}
__device__ __forceinline__ float sigmoid_f(float x){
    return 1.f / (1.f + __expf(-x));
}
__device__ __forceinline__ float tanh_f(float x){
    float e = __expf(2.f * x);
    return 1.f - 2.f / (e + 1.f);
}
__device__ __forceinline__ short f2bf(float f){
    unsigned u = __builtin_bit_cast(unsigned, f);
    unsigned r = (u + 0x7FFFu + ((u >> 16) & 1u)) >> 16;
    return (short)r;
}

// ---------------- signatures: s1 (B,NWIN,D), s2 (B,NWIN,P) ----------------
__global__ void sig_kernel(const float* __restrict__ x,
                           float* __restrict__ s1o, float* __restrict__ s2o){
    int w = blockIdx.x * blockDim.x + threadIdx.x;
    if (w >= BB * NWIN) return;
    int b = w >> 7, n = w & (NWIN - 1);
    const float* xp = x + ((size_t)b * TT + (size_t)n * WINW) * DD;
    float prev[DD], cum[DD], s1v[DD], M[DD][DD];
    #pragma unroll
    for (int i = 0; i < DD; ++i){
        cum[i] = 0.f; s1v[i] = 0.f;
        #pragma unroll
        for (int j = 0; j < DD; ++j) M[i][j] = 0.f;
    }
    #pragma unroll
    for (int i = 0; i < DD; ++i) prev[i] = xp[i];
    for (int t = 0; t < WINW; ++t){
        float cur[DD], del[DD];
        #pragma unroll
        for (int i = 0; i < DD; ++i) cur[i] = xp[(t + 1) * DD + i];
        #pragma unroll
        for (int i = 0; i < DD; ++i) del[i] = cur[i] - prev[i];
        #pragma unroll
        for (int i = 0; i < DD; ++i){
            #pragma unroll
            for (int j = 0; j < DD; ++j) M[i][j] += cum[i] * del[j];
        }
        #pragma unroll
        for (int i = 0; i < DD; ++i){ cum[i] += del[i]; s1v[i] += del[i]; prev[i] = cur[i]; }
    }
    #pragma unroll
    for (int i = 0; i < DD; ++i) s1o[(size_t)w * DD + i] = s1v[i];
    int p = 0;
    #pragma unroll
    for (int i = 0; i < DD; ++i){
        #pragma unroll
        for (int j = i + 1; j < DD; ++j){ s2o[(size_t)w * PP + p] = 0.5f * (M[i][j] - M[j][i]); ++p; }
    }
}

// ---------------- main scan: one block per batch element, MFMA-based ----------------
__global__ __launch_bounds__(512, 2) void scan_kernel(
    const float* __restrict__ x,
    const float* __restrict__ Wi0, const float* __restrict__ bi0,
    const float* __restrict__ Wi1, const float* __restrict__ bi1,
    const float* __restrict__ Wi2, const float* __restrict__ bi2,
    const float* __restrict__ Wv0, const float* __restrict__ bv0,
    const float* __restrict__ Wv1, const float* __restrict__ bv1,
    const float* __restrict__ Wv2, const float* __restrict__ bv2,
    const float* __restrict__ Wr,  const float* __restrict__ br,
    const float* __restrict__ s1g, const float* __restrict__ s2g,
    float* __restrict__ out)
{
    const int tid = threadIdx.x;
    const int b   = blockIdx.x;
    const int w   = tid >> 6;   // wave 0..7
    const int l   = tid & 63;   // lane
    const int lg  = l >> 4;     // lane group 0..3
    const int ln  = l & 15;     // n-column within MFMA tile

    __shared__ __align__(16) float z0f[HH], s0p[HH], z1f[HH], s1pL[HH];
    __shared__ __align__(16) float hf[SS];
    __shared__ __align__(16) float Vl[DD * SS];
    __shared__ __align__(16) float Rf[DD * SS];
    __shared__ __align__(16) float bv0L[HH], bv1L[HH], bv2L[DD * SS];
    __shared__ __align__(16) float WrL[OUTD * SS];
    __shared__ float brL[OUTD], aL[DD], bcoL[PP];
    // packed B-fragment images (bf16): Bp[ks][lane][j]  == B[ks*32 + (lane>>4)*8 + j][lane&15]
    __shared__ __align__(16) short Bp7[2][64][8];
    __shared__ __align__(16) short Bp8[4][64][8];
    __shared__ __align__(16) short Bp9[4][64][8];

    // -------- persistent bf16 A-fragments (weights) --------
    // A-frag layout for 16x16x32: lane l holds A[l&15][(l>>4)*8 + j], j=0..7
    short8v A0f[2], A1f[4], A2f[4][4];
    {
        const int row = w * 16 + ln;
        #pragma unroll
        for (int ks = 0; ks < 2; ++ks){
            const float* p = Wv0 + (size_t)row * SS + ks * 32 + lg * 8;
            short8v f;
            #pragma unroll
            for (int j = 0; j < 8; ++j) f[j] = f2bf(p[j]);
            A0f[ks] = f;
        }
        #pragma unroll
        for (int ks = 0; ks < 4; ++ks){
            const float* p = Wv1 + (size_t)row * HH + ks * 32 + lg * 8;
            short8v f;
            #pragma unroll
            for (int j = 0; j < 8; ++j) f[j] = f2bf(p[j]);
            A1f[ks] = f;
        }
        #pragma unroll
        for (int t = 0; t < 4; ++t){
            const int r2 = 64 * w + t * 16 + ln;
            #pragma unroll
            for (int ks = 0; ks < 4; ++ks){
                const float* p = Wv2 + (size_t)r2 * HH + ks * 32 + lg * 8;
                short8v f;
                #pragma unroll
                for (int j = 0; j < 8; ++j) f[j] = f2bf(p[j]);
                A2f[t][ks] = f;
            }
        }
    }
    if (tid < HH){ bv0L[tid] = bv0[tid]; bv1L[tid] = bv1[tid]; }
    bv2L[tid] = bv2[tid];
    WrL[tid]  = Wr[tid];
    if (tid < OUTD) brL[tid] = br[tid];
    {   // zero packed images once (pad columns 8..15 stay zero forever)
        short* p7 = &Bp7[0][0][0];
        short* p8 = &Bp8[0][0][0];
        short* p9 = &Bp9[0][0][0];
        for (int i = tid; i < 2 * 64 * 8; i += 512) p7[i] = 0;
        for (int i = tid; i < 4 * 64 * 8; i += 512) p8[i] = 0;
        for (int i = tid; i < 4 * 64 * 8; i += 512) p9[i] = 0;
    }
    __syncthreads();

    // -------- initial MLP (f32, once) --------
    if (tid < HH){
        float acc = bi0[tid];
        const float* x0 = x + (size_t)b * TT * DD;
        #pragma unroll
        for (int c = 0; c < DD; ++c) acc += Wi0[tid * DD + c] * x0[c];
        z0f[tid] = softplus_f(acc);
    }
    __syncthreads();
    if (tid < HH){
        float acc = bi1[tid];
        #pragma unroll 4
        for (int c = 0; c < HH; ++c) acc += Wi1[(size_t)tid * HH + c] * z0f[c];
        z1f[tid] = softplus_f(acc);
    }
    __syncthreads();
    if (tid < SS){
        float acc = bi2[tid];
        #pragma unroll 4
        for (int c = 0; c < HH; ++c) acc += Wi2[(size_t)tid * HH + c] * z1f[c];
        hf[tid] = acc;
    }
    __syncthreads();
    {   // h0 readout: wave w computes output channel w via shuffle reduction
        float p = WrL[w * SS + l] * hf[l];
        #pragma unroll
        for (int off = 32; off; off >>= 1) p += __shfl_down(p, off);
        if (l == 0) out[(size_t)b * (NWIN + 1) * OUTD + w] = brL[w] + p;
    }

    // B-fragment builder for N=1 GEMVs: col 0 = vec, cols 1..15 = 0
    auto bfragN1 = [&](const float* vec, int ks) -> short8v {
        f32x4 lo = *(const f32x4*)(vec + ks * 32 + lg * 8);
        f32x4 hi = *(const f32x4*)(vec + ks * 32 + lg * 8 + 4);
        short8v f;
        #pragma unroll
        for (int j = 0; j < 4; ++j){
            f[j]     = f2bf(ln == 0 ? lo[j] : 0.f);
            f[j + 4] = f2bf(ln == 0 ? hi[j] : 0.f);
        }
        return f;
    };
    const f32x4 zero4 = {0.f, 0.f, 0.f, 0.f};

    // -------- scan over NWIN windows --------
    for (int n = 0; n < NWIN; ++n){
        if (tid < DD) aL[tid]   = s1g[((size_t)b * NWIN + n) * DD + tid];
        if (tid < PP) bcoL[tid] = s2g[((size_t)b * NWIN + n) * PP + tid];

        // S1: z0pre = W0 @ h   (M=128,K=64,N=1)
        {
            f32x4 acc = zero4;
            acc = __builtin_amdgcn_mfma_f32_16x16x32_bf16(A0f[0], bfragN1(hf, 0), acc, 0, 0, 0);
            acc = __builtin_amdgcn_mfma_f32_16x16x32_bf16(A0f[1], bfragN1(hf, 1), acc, 0, 0, 0);
            if (ln == 0){
                int rb = w * 16 + lg * 4;
                f32x4 bv = *(const f32x4*)&bv0L[rb];
                f32x4 zz, ss;
                #pragma unroll
                for (int r = 0; r < 4; ++r){
                    float p0 = acc[r] + bv[r];
                    zz[r] = softplus_f(p0); ss[r] = sigmoid_f(p0);
                }
                *(f32x4*)&z0f[rb] = zz; *(f32x4*)&s0p[rb] = ss;
            }
        }
        __syncthreads();

        // S3: z1pre = W1 @ z0  (M=128,K=128,N=1)
        {
            f32x4 acc = zero4;
            #pragma unroll
            for (int ks = 0; ks < 4; ++ks)
                acc = __builtin_amdgcn_mfma_f32_16x16x32_bf16(A1f[ks], bfragN1(z0f, ks), acc, 0, 0, 0);
            if (ln == 0){
                int rb = w * 16 + lg * 4;
                f32x4 bv = *(const f32x4*)&bv1L[rb];
                f32x4 zz, ss;
                #pragma unroll
                for (int r = 0; r < 4; ++r){
                    float p1 = acc[r] + bv[r];
                    zz[r] = softplus_f(p1); ss[r] = sigmoid_f(p1);
                }
                *(f32x4*)&z1f[rb] = zz; *(f32x4*)&s1pL[rb] = ss;
            }
        }
        __syncthreads();

        // S4: V = tanh(W2 @ z1 + bv2)  (M=512,K=128,N=1); wave w owns rows 64w..64w+63 (d=w)
        {
            short8v Bz[4];
            #pragma unroll
            for (int ks = 0; ks < 4; ++ks) Bz[ks] = bfragN1(z1f, ks);
            f32x4 acc[4];
            #pragma unroll
            for (int t = 0; t < 4; ++t) acc[t] = zero4;
            #pragma unroll
            for (int t = 0; t < 4; ++t)
                #pragma unroll
                for (int ks = 0; ks < 4; ++ks)
                    acc[t] = __builtin_amdgcn_mfma_f32_16x16x32_bf16(A2f[t][ks], Bz[ks], acc[t], 0, 0, 0);
            if (ln == 0){
                #pragma unroll
                for (int t = 0; t < 4; ++t){
                    int rb = 64 * w + t * 16 + lg * 4;
                    f32x4 bv = *(const f32x4*)&bv2L[rb];
                    f32x4 vv;
                    #pragma unroll
                    for (int r = 0; r < 4; ++r) vv[r] = tanh_f(acc[t][r] + bv[r]);
                    *(f32x4*)&Vl[rb] = vv;
                }
            }
        }
        __syncthreads();

        // u[d][c] = sum_e C[d][e] V[e][c]; wave w handles d=w, lane l -> c=l.
        // Write straight into packed B-image for S7: B7[k=c][n=d]
        {
            float accu = 0.f;
            #pragma unroll
            for (int e = 0; e < DD; ++e){
                float coef;
                if (e == w)      coef = 0.f;
                else if (e < w)  coef =  bcoL[((e * (15 - e)) >> 1) + w - e - 1];
                else             coef = -bcoL[((w * (15 - w)) >> 1) + e - w - 1];
                accu += coef * Vl[e * SS + l];
            }
            Bp7[l >> 5][((l >> 3) & 3) * 16 + w][l & 7] = f2bf(accu);
        }
        __syncthreads();

        // S7: t0 = s0' * (W0 @ u)  (M=128,K=64,N=8) -> packed B-image for S8
        {
            f32x4 acc = zero4;
            acc = __builtin_amdgcn_mfma_f32_16x16x32_bf16(A0f[0], *(const short8v*)&Bp7[0][l][0], acc, 0, 0, 0);
            acc = __builtin_amdgcn_mfma_f32_16x16x32_bf16(A0f[1], *(const short8v*)&Bp7[1][l][0], acc, 0, 0, 0);
            int rb = w * 16 + lg * 4;
            f32x4 sv = *(const f32x4*)&s0p[rb];
            if (ln < 8){
                #pragma unroll
                for (int r = 0; r < 4; ++r){
                    int rr = rb + r;
                    Bp8[rr >> 5][((rr >> 3) & 3) * 16 + ln][rr & 7] = f2bf(sv[r] * acc[r]);
                }
            }
        }
        __syncthreads();

        // S8: q = s1' * (W1 @ t0)  (M=128,K=128,N=8) -> packed B-image for S9
        {
            f32x4 acc = zero4;
            #pragma unroll
            for (int ks = 0; ks < 4; ++ks)
                acc = __builtin_amdgcn_mfma_f32_16x16x32_bf16(A1f[ks], *(const short8v*)&Bp8[ks][l][0], acc, 0, 0, 0);
            int rb = w * 16 + lg * 4;
            f32x4 sv = *(const f32x4*)&s1pL[rb];
            if (ln < 8){
                #pragma unroll
                for (int r = 0; r < 4; ++r){
                    int rr = rb + r;
                    Bp9[rr >> 5][((rr >> 3) & 3) * 16 + ln][rr & 7] = f2bf(sv[r] * acc[r]);
                }
            }
        }
        __syncthreads();

        // S9: R-block d=w: (1-V^2) * (W2[64w..][:] @ q[:,w])  (M=512,K=128,N=8, use col w)
        {
            short8v B9[4];
            #pragma unroll
            for (int ks = 0; ks < 4; ++ks) B9[ks] = *(const short8v*)&Bp9[ks][l][0];
            f32x4 acc[4];
            #pragma unroll
            for (int t = 0; t < 4; ++t) acc[t] = zero4;
            #pragma unroll
            for (int t = 0; t < 4; ++t)
                #pragma unroll
                for (int ks = 0; ks < 4; ++ks)
                    acc[t] = __builtin_amdgcn_mfma_f32_16x16x32_bf16(A2f[t][ks], B9[ks], acc[t], 0, 0, 0);
            if (ln == w){
                #pragma unroll
                for (int t = 0; t < 4; ++t){
                    int rb = 64 * w + t * 16 + lg * 4;
                    f32x4 vv = *(const f32x4*)&Vl[rb];
                    f32x4 rr;
                    #pragma unroll
                    for (int r = 0; r < 4; ++r) rr[r] = (1.f - vv[r] * vv[r]) * acc[t][r];
                    *(f32x4*)&Rf[rb] = rr;
                }
            }
        }
        __syncthreads();

        // h update: hn = h + a@V + sum_d R[d]
        if (tid < SS){
            float y = 0.f, av = 0.f;
            #pragma unroll
            for (int d = 0; d < DD; ++d){
                y  += Rf[d * SS + tid];
                av += aL[d] * Vl[d * SS + tid];
            }
            hf[tid] += av + y;
        }
        __syncthreads();

        // readout: wave w -> output channel w
        {
            float p = WrL[w * SS + l] * hf[l];
            #pragma unroll
            for (int off = 32; off; off >>= 1) p += __shfl_down(p, off);
            if (l == 0) out[(size_t)b * (NWIN + 1) * OUTD + (size_t)(n + 1) * OUTD + w] = brL[w] + p;
        }
    }
}

extern "C" void kernel_launch(void* const* d_in, const int* in_sizes, int n_in,
                              void* d_out, int out_size, void* d_ws, size_t ws_size,
                              hipStream_t stream){
    const float* x   = (const float*)d_in[1];
    const float* Wi0 = (const float*)d_in[2];
    const float* bi0 = (const float*)d_in[3];
    const float* Wi1 = (const float*)d_in[4];
    const float* bi1 = (const float*)d_in[5];
    const float* Wi2 = (const float*)d_in[6];
    const float* bi2 = (const float*)d_in[7];
    const float* Wv0 = (const float*)d_in[8];
    const float* bv0 = (const float*)d_in[9];
    const float* Wv1 = (const float*)d_in[10];
    const float* bv1 = (const float*)d_in[11];
    const float* Wv2 = (const float*)d_in[12];
    const float* bv2 = (const float*)d_in[13];
    const float* Wr  = (const float*)d_in[14];
    const float* br  = (const float*)d_in[15];
    float* out = (float*)d_out;

    float* s1w = (float*)d_ws;
    float* s2w = s1w + (size_t)BB * NWIN * DD;

    sig_kernel<<<(BB * NWIN + 255) / 256, 256, 0, stream>>>(x, s1w, s2w);
    scan_kernel<<<BB, 512, 0, stream>>>(x, Wi0, bi0, Wi1, bi1, Wi2, bi2,
                                        Wv0, bv0, Wv1, bv1, Wv2, bv2,
                                        Wr, br, s1w, s2w, out);
}

// Round 4
// 1989.735 us; speedup vs baseline: 1.0240x; 1.0240x over previous
//
#include <hip/hip_runtime.h>

#define DD 8
#define SS 64
#define HH 128
#define OUTD 8
#define TT 2049
#define BB 32
#define WINW 16
#define NWIN 128
#define PP 28

typedef __attribute__((ext_vector_type(8))) short short8v;
typedef __attribute__((ext_vector_type(4))) float f32x4;

__device__ __forceinline__ float softplus_f(float x){
    return fmaxf(x, 0.f) + log1pf(__expf(-fabsf(x)));
}
__device__ __forceinline__ float sigmoid_f(float x){
    return 1.f / (1.f + __expf(-x));
}
__device__ __forceinline__ float tanh_f(float x){
    float e = __expf(2.f * x);
    return 1.f - 2.f / (e + 1.f);
}
__device__ __forceinline__ unsigned short f2bf(float f){
    unsigned u = __builtin_bit_cast(unsigned, f);
    unsigned r = (u + 0x7FFFu + ((u >> 16) & 1u)) >> 16;
    return (unsigned short)r;
}
__device__ __forceinline__ unsigned pk2(float a, float b){
    return (unsigned)f2bf(a) | ((unsigned)f2bf(b) << 16);
}

// ---------------- signatures: s1 (B,NWIN,D), s2 (B,NWIN,P) ----------------
__global__ void sig_kernel(const float* __restrict__ x,
                           float* __restrict__ s1o, float* __restrict__ s2o){
    int w = blockIdx.x * blockDim.x + threadIdx.x;
    if (w >= BB * NWIN) return;
    int b = w >> 7, n = w & (NWIN - 1);
    const float* xp = x + ((size_t)b * TT + (size_t)n * WINW) * DD;
    float prev[DD], cum[DD], s1v[DD], M[DD][DD];
    #pragma unroll
    for (int i = 0; i < DD; ++i){
        cum[i] = 0.f; s1v[i] = 0.f;
        #pragma unroll
        for (int j = 0; j < DD; ++j) M[i][j] = 0.f;
    }
    #pragma unroll
    for (int i = 0; i < DD; ++i) prev[i] = xp[i];
    for (int t = 0; t < WINW; ++t){
        float cur[DD], del[DD];
        #pragma unroll
        for (int i = 0; i < DD; ++i) cur[i] = xp[(t + 1) * DD + i];
        #pragma unroll
        for (int i = 0; i < DD; ++i) del[i] = cur[i] - prev[i];
        #pragma unroll
        for (int i = 0; i < DD; ++i){
            #pragma unroll
            for (int j = 0; j < DD; ++j) M[i][j] += cum[i] * del[j];
        }
        #pragma unroll
        for (int i = 0; i < DD; ++i){ cum[i] += del[i]; s1v[i] += del[i]; prev[i] = cur[i]; }
    }
    #pragma unroll
    for (int i = 0; i < DD; ++i) s1o[(size_t)w * DD + i] = s1v[i];
    int p = 0;
    #pragma unroll
    for (int i = 0; i < DD; ++i){
        #pragma unroll
        for (int j = i + 1; j < DD; ++j){ s2o[(size_t)w * PP + p] = 0.5f * (M[i][j] - M[j][i]); ++p; }
    }
}

// image position helper (in shorts): k-row k, col nn of a [K/32][64][8] B-image
#define BPOS(k, nn) ((((k) >> 5) * 64 + (((k) >> 3) & 3) * 16 + (nn)) * 8 + ((k) & 7))

// ---------------- main scan: 2 chains per block, 16 waves, MFMA ----------------
__global__ __launch_bounds__(1024, 4) void scan_kernel(
    const float* __restrict__ x,
    const float* __restrict__ Wi0, const float* __restrict__ bi0,
    const float* __restrict__ Wi1, const float* __restrict__ bi1,
    const float* __restrict__ Wi2, const float* __restrict__ bi2,
    const float* __restrict__ Wv0, const float* __restrict__ bv0,
    const float* __restrict__ Wv1, const float* __restrict__ bv1,
    const float* __restrict__ Wv2, const float* __restrict__ bv2,
    const float* __restrict__ Wr,  const float* __restrict__ br,
    const float* __restrict__ s1g, const float* __restrict__ s2g,
    float* __restrict__ out)
{
    const int tid = threadIdx.x;
    const int w   = tid >> 6;   // wave 0..15
    const int l   = tid & 63;   // lane
    const int lg  = l >> 4;     // lane group 0..3
    const int ln  = l & 15;     // n-col within MFMA tile
    const int b0  = blockIdx.x * 2;

    // A-fragment images (bf16) for W0 (8 m-tiles x 2 ks) and W1 (8 x 4)
    __shared__ __align__(16) short A0img[8 * 2 * 64 * 8];   // 16 KB
    __shared__ __align__(16) short A1img[8 * 4 * 64 * 8];   // 32 KB
    // B-fragment images
    __shared__ __align__(16) short BpH[2 * 64 * 8];         // h   (K=64,  N=2)
    __shared__ __align__(16) short Bp0[4 * 64 * 8];         // z0  (K=128, N=2)
    __shared__ __align__(16) short Bp1[4 * 64 * 8];         // z1  (K=128, N=2)
    __shared__ __align__(16) short Bp7[2 * 64 * 8];         // u   (K=64,  N=16)
    __shared__ __align__(16) short Bp8[4 * 64 * 8];         // t0  (K=128, N=16)
    __shared__ __align__(16) short Bp9[4 * 64 * 8];         // q   (K=128, N=16)
    __shared__ __align__(16) float s0p[2 * HH], s1p[2 * HH];
    __shared__ __align__(16) float Vl[2 * 512], Rf[2 * 512];
    __shared__ __align__(16) float hf[2 * SS];
    __shared__ __align__(16) float bv0L[HH], bv1L[HH], bv2L[512];
    __shared__ __align__(16) float WrL[OUTD * SS];
    __shared__ float brL[OUTD];
    __shared__ __align__(16) float sAll[2 * NWIN * DD];     // 8 KB
    __shared__ __align__(16) float bAll[2 * NWIN * PP];     // 28 KB
    __shared__ __align__(16) float outL[2 * (NWIN + 1) * OUTD]; // 8.25 KB

    // -------- prologue: pack weight images, load W2 reg-frags, stage signatures --------
    for (int i = tid; i < 8 * 2 * 64 * 8; i += 1024){
        int m = i >> 10, ks = (i >> 9) & 1, ll = (i >> 3) & 63, j = i & 7;
        A0img[i] = (short)f2bf(Wv0[(m * 16 + (ll & 15)) * SS + ks * 32 + (ll >> 4) * 8 + j]);
    }
    for (int i = tid; i < 8 * 4 * 64 * 8; i += 1024){
        int m = i >> 11, ks = (i >> 9) & 3, ll = (i >> 3) & 63, j = i & 7;
        A1img[i] = (short)f2bf(Wv1[(m * 16 + (ll & 15)) * HH + ks * 32 + (ll >> 4) * 8 + j]);
    }
    short8v A2f[2][4];   // W2 rows 32w .. 32w+31
    #pragma unroll
    for (int t = 0; t < 2; ++t)
        #pragma unroll
        for (int ks = 0; ks < 4; ++ks){
            const float* p = Wv2 + (size_t)(32 * w + t * 16 + ln) * HH + ks * 32 + lg * 8;
            short8v f;
            #pragma unroll
            for (int j = 0; j < 8; ++j) f[j] = (short)f2bf(p[j]);
            A2f[t][ks] = f;
        }
    if (tid < HH){ bv0L[tid] = bv0[tid]; bv1L[tid] = bv1[tid]; }
    if (tid < 512){ bv2L[tid] = bv2[tid]; WrL[tid] = Wr[tid]; }
    if (tid < OUTD) brL[tid] = br[tid];
    for (int i = tid; i < 2 * NWIN * DD; i += 1024){
        int c = i >> 10;
        sAll[i] = s1g[(size_t)(b0 + c) * NWIN * DD + (i & 1023)];
    }
    for (int i = tid; i < 2 * NWIN * PP; i += 1024){
        int c = i / (NWIN * PP);
        bAll[i] = s2g[(size_t)(b0 + c) * NWIN * PP + (i - c * NWIN * PP)];
    }
    __syncthreads();

    // -------- initial MLP (f32, once); reuse s0p/s1p as scratch --------
    if (tid < 256){
        int c = tid >> 7, r = tid & 127;
        float acc = bi0[r];
        const float* x0 = x + (size_t)(b0 + c) * TT * DD;
        #pragma unroll
        for (int k = 0; k < DD; ++k) acc += Wi0[r * DD + k] * x0[k];
        s0p[c * HH + r] = softplus_f(acc);
    }
    __syncthreads();
    if (tid < 256){
        int c = tid >> 7, r = tid & 127;
        float acc = bi1[r];
        const f32x4* wv = (const f32x4*)(Wi1 + (size_t)r * HH);
        const f32x4* zv = (const f32x4*)&s0p[c * HH];
        #pragma unroll 8
        for (int k = 0; k < 32; ++k){
            f32x4 a = wv[k], z = zv[k];
            acc += a.x * z.x + a.y * z.y + a.z * z.z + a.w * z.w;
        }
        s1p[c * HH + r] = softplus_f(acc);
    }
    __syncthreads();
    if (tid < 128){
        int c = tid >> 6, s = tid & 63;
        float acc = bi2[s];
        const f32x4* wv = (const f32x4*)(Wi2 + (size_t)s * HH);
        const f32x4* zv = (const f32x4*)&s1p[c * HH];
        #pragma unroll 8
        for (int k = 0; k < 32; ++k){
            f32x4 a = wv[k], z = zv[k];
            acc += a.x * z.x + a.y * z.y + a.z * z.z + a.w * z.w;
        }
        hf[c * SS + s] = acc;
        BpH[BPOS(s, c)] = (short)f2bf(acc);
    }
    __syncthreads();

    const f32x4 zero4 = {0.f, 0.f, 0.f, 0.f};

    // -------- scan --------
    for (int n = 0; n < NWIN; ++n){
        // ---- stage A: S1 (waves 0-7) || readout h_n (waves 8-9) ----
        if (w < 8){
            f32x4 acc = zero4;
            #pragma unroll
            for (int ks = 0; ks < 2; ++ks)
                acc = __builtin_amdgcn_mfma_f32_16x16x32_bf16(
                    *(const short8v*)&A0img[((w * 2 + ks) * 64 + l) * 8],
                    *(const short8v*)&BpH[(ks * 64 + l) * 8], acc, 0, 0, 0);
            if (ln < 2){
                int c = ln, rb = w * 16 + lg * 4;
                f32x4 bv = *(const f32x4*)&bv0L[rb];
                f32x4 sg; float z[4];
                #pragma unroll
                for (int r = 0; r < 4; ++r){
                    float p = acc[r] + bv[r];
                    z[r] = softplus_f(p); sg[r] = sigmoid_f(p);
                }
                *(f32x4*)&s0p[c * HH + rb] = sg;
                uint2 pk; pk.x = pk2(z[0], z[1]); pk.y = pk2(z[2], z[3]);
                *(uint2*)&Bp0[BPOS(rb, c)] = pk;
            }
        } else if (w < 10){
            int c = w - 8, o = l >> 3, q = l & 7;
            f32x4 w0 = *(const f32x4*)&WrL[o * SS + q * 8];
            f32x4 w1 = *(const f32x4*)&WrL[o * SS + q * 8 + 4];
            f32x4 h0 = *(const f32x4*)&hf[c * SS + q * 8];
            f32x4 h1 = *(const f32x4*)&hf[c * SS + q * 8 + 4];
            float acc = w0.x*h0.x + w0.y*h0.y + w0.z*h0.z + w0.w*h0.w
                      + w1.x*h1.x + w1.y*h1.y + w1.z*h1.z + w1.w*h1.w;
            acc += __shfl_xor(acc, 1); acc += __shfl_xor(acc, 2); acc += __shfl_xor(acc, 4);
            if (q == 0) outL[c * (NWIN + 1) * OUTD + n * OUTD + o] = brL[o] + acc;
        }
        __syncthreads();

        // ---- S3: z1 = sp(W1 @ z0) (waves 0-7) ----
        if (w < 8){
            f32x4 acc = zero4;
            #pragma unroll
            for (int ks = 0; ks < 4; ++ks)
                acc = __builtin_amdgcn_mfma_f32_16x16x32_bf16(
                    *(const short8v*)&A1img[((w * 4 + ks) * 64 + l) * 8],
                    *(const short8v*)&Bp0[(ks * 64 + l) * 8], acc, 0, 0, 0);
            if (ln < 2){
                int c = ln, rb = w * 16 + lg * 4;
                f32x4 bv = *(const f32x4*)&bv1L[rb];
                f32x4 sg; float z[4];
                #pragma unroll
                for (int r = 0; r < 4; ++r){
                    float p = acc[r] + bv[r];
                    z[r] = softplus_f(p); sg[r] = sigmoid_f(p);
                }
                *(f32x4*)&s1p[c * HH + rb] = sg;
                uint2 pk; pk.x = pk2(z[0], z[1]); pk.y = pk2(z[2], z[3]);
                *(uint2*)&Bp1[BPOS(rb, c)] = pk;
            }
        }
        __syncthreads();

        // ---- S4: V = tanh(W2 @ z1 + bv2) (all 16 waves, rows 32w..32w+31) ----
        {
            f32x4 acc0 = zero4, acc1 = zero4;
            #pragma unroll
            for (int ks = 0; ks < 4; ++ks){
                short8v bfr = *(const short8v*)&Bp1[(ks * 64 + l) * 8];
                acc0 = __builtin_amdgcn_mfma_f32_16x16x32_bf16(A2f[0][ks], bfr, acc0, 0, 0, 0);
                acc1 = __builtin_amdgcn_mfma_f32_16x16x32_bf16(A2f[1][ks], bfr, acc1, 0, 0, 0);
            }
            if (ln < 2){
                int c = ln;
                #pragma unroll
                for (int t = 0; t < 2; ++t){
                    int rb = 32 * w + t * 16 + lg * 4;
                    f32x4 av = t ? acc1 : acc0;
                    f32x4 bv = *(const f32x4*)&bv2L[rb];
                    f32x4 vv;
                    #pragma unroll
                    for (int r = 0; r < 4; ++r) vv[r] = tanh_f(av[r] + bv[r]);
                    *(f32x4*)&Vl[c * 512 + rb] = vv;
                }
            }
        }
        __syncthreads();

        // ---- u[d] = sum_e C[d][e] V[e]  (256 threads; 4 cols each -> Bp7) ----
        if (tid < 256){
            int c = tid >> 7, d = (tid >> 4) & 7, cg = tid & 15;
            const float* bco = &bAll[c * (NWIN * PP) + n * PP];
            f32x4 acc = zero4;
            #pragma unroll
            for (int e = 0; e < DD; ++e){
                if (e == d) continue;
                float coef = (e < d) ?  bco[((e * (15 - e)) >> 1) + d - e - 1]
                                     : -bco[((d * (15 - d)) >> 1) + e - d - 1];
                f32x4 v4 = *(const f32x4*)&Vl[c * 512 + e * 64 + cg * 4];
                acc.x += coef * v4.x; acc.y += coef * v4.y;
                acc.z += coef * v4.z; acc.w += coef * v4.w;
            }
            int k0 = cg * 4, nn = c * 8 + d;
            uint2 pk; pk.x = pk2(acc.x, acc.y); pk.y = pk2(acc.z, acc.w);
            *(uint2*)&Bp7[BPOS(k0, nn)] = pk;
        }
        __syncthreads();

        // ---- S7: t0 = s0' * (W0 @ u) (waves 8-15, all 16 cols) ----
        if (w >= 8){
            int mt = w - 8;
            f32x4 acc = zero4;
            #pragma unroll
            for (int ks = 0; ks < 2; ++ks)
                acc = __builtin_amdgcn_mfma_f32_16x16x32_bf16(
                    *(const short8v*)&A0img[((mt * 2 + ks) * 64 + l) * 8],
                    *(const short8v*)&Bp7[(ks * 64 + l) * 8], acc, 0, 0, 0);
            int c = ln >> 3, rb = mt * 16 + lg * 4;
            f32x4 sg = *(const f32x4*)&s0p[c * HH + rb];
            uint2 pk; pk.x = pk2(sg[0] * acc[0], sg[1] * acc[1]);
            pk.y = pk2(sg[2] * acc[2], sg[3] * acc[3]);
            *(uint2*)&Bp8[BPOS(rb, ln)] = pk;
        }
        __syncthreads();

        // ---- S8: q = s1' * (W1 @ t0) (waves 0-7) ----
        if (w < 8){
            f32x4 acc = zero4;
            #pragma unroll
            for (int ks = 0; ks < 4; ++ks)
                acc = __builtin_amdgcn_mfma_f32_16x16x32_bf16(
                    *(const short8v*)&A1img[((w * 4 + ks) * 64 + l) * 8],
                    *(const short8v*)&Bp8[(ks * 64 + l) * 8], acc, 0, 0, 0);
            int c = ln >> 3, rb = w * 16 + lg * 4;
            f32x4 sg = *(const f32x4*)&s1p[c * HH + rb];
            uint2 pk; pk.x = pk2(sg[0] * acc[0], sg[1] * acc[1]);
            pk.y = pk2(sg[2] * acc[2], sg[3] * acc[3]);
            *(uint2*)&Bp9[BPOS(rb, ln)] = pk;
        }
        __syncthreads();

        // ---- S9: R = (1-V^2) * (W2 @ q), diagonal col d=w>>1 (all waves) ----
        {
            f32x4 acc0 = zero4, acc1 = zero4;
            #pragma unroll
            for (int ks = 0; ks < 4; ++ks){
                short8v bfr = *(const short8v*)&Bp9[(ks * 64 + l) * 8];
                acc0 = __builtin_amdgcn_mfma_f32_16x16x32_bf16(A2f[0][ks], bfr, acc0, 0, 0, 0);
                acc1 = __builtin_amdgcn_mfma_f32_16x16x32_bf16(A2f[1][ks], bfr, acc1, 0, 0, 0);
            }
            int dtar = w >> 1;
            if ((ln & 7) == dtar){
                int c = ln >> 3;
                #pragma unroll
                for (int t = 0; t < 2; ++t){
                    int rb = 32 * w + t * 16 + lg * 4;
                    f32x4 av = t ? acc1 : acc0;
                    f32x4 vv = *(const f32x4*)&Vl[c * 512 + rb];
                    f32x4 rr;
                    #pragma unroll
                    for (int r = 0; r < 4; ++r) rr[r] = (1.f - vv[r] * vv[r]) * av[r];
                    *(f32x4*)&Rf[c * 512 + rb] = rr;
                }
            }
        }
        __syncthreads();

        // ---- h update ----
        if (tid < 128){
            int c = tid >> 6, s = tid & 63;
            const float* aL = &sAll[c * (NWIN * DD) + n * DD];
            float av = 0.f, y = 0.f;
            #pragma unroll
            for (int d = 0; d < DD; ++d){
                av += aL[d] * Vl[c * 512 + d * 64 + s];
                y  += Rf[c * 512 + d * 64 + s];
            }
            float hn = hf[c * SS + s] + av + y;
            hf[c * SS + s] = hn;
            BpH[BPOS(s, c)] = (short)f2bf(hn);
        }
        __syncthreads();
    }

    // final readout h_NWIN
    if (w == 8 || w == 9){
        int c = w - 8, o = l >> 3, q = l & 7;
        f32x4 w0 = *(const f32x4*)&WrL[o * SS + q * 8];
        f32x4 w1 = *(const f32x4*)&WrL[o * SS + q * 8 + 4];
        f32x4 h0 = *(const f32x4*)&hf[c * SS + q * 8];
        f32x4 h1 = *(const f32x4*)&hf[c * SS + q * 8 + 4];
        float acc = w0.x*h0.x + w0.y*h0.y + w0.z*h0.z + w0.w*h0.w
                  + w1.x*h1.x + w1.y*h1.y + w1.z*h1.z + w1.w*h1.w;
        acc += __shfl_xor(acc, 1); acc += __shfl_xor(acc, 2); acc += __shfl_xor(acc, 4);
        if (q == 0) outL[c * (NWIN + 1) * OUTD + NWIN * OUTD + o] = brL[o] + acc;
    }
    __syncthreads();

    // flush outputs
    for (int i = tid; i < 2 * (NWIN + 1) * OUTD; i += 1024){
        int c = (i >= (NWIN + 1) * OUTD) ? 1 : 0;
        int rem = i - c * (NWIN + 1) * OUTD;
        out[(size_t)(b0 + c) * (NWIN + 1) * OUTD + rem] = outL[i];
    }
}

extern "C" void kernel_launch(void* const* d_in, const int* in_sizes, int n_in,
                              void* d_out, int out_size, void* d_ws, size_t ws_size,
                              hipStream_t stream){
    const float* x   = (const float*)d_in[1];
    const float* Wi0 = (const float*)d_in[2];
    const float* bi0 = (const float*)d_in[3];
    const float* Wi1 = (const float*)d_in[4];
    const float* bi1 = (const float*)d_in[5];
    const float* Wi2 = (const float*)d_in[6];
    const float* bi2 = (const float*)d_in[7];
    const float* Wv0 = (const float*)d_in[8];
    const float* bv0 = (const float*)d_in[9];
    const float* Wv1 = (const float*)d_in[10];
    const float* bv1 = (const float*)d_in[11];
    const float* Wv2 = (const float*)d_in[12];
    const float* bv2 = (const float*)d_in[13];
    const float* Wr  = (const float*)d_in[14];
    const float* br  = (const float*)d_in[15];
    float* out = (float*)d_out;

    float* s1w = (float*)d_ws;
    float* s2w = s1w + (size_t)BB * NWIN * DD;

    sig_kernel<<<(BB * NWIN + 255) / 256, 256, 0, stream>>>(x, s1w, s2w);
    scan_kernel<<<BB / 2, 1024, 0, stream>>>(x, Wi0, bi0, Wi1, bi1, Wi2, bi2,
                                             Wv0, bv0, Wv1, bv1, Wv2, bv2,
                                             Wr, br, s1w, s2w, out);
}